// Round 2
// baseline (896.121 us; speedup 1.0000x reference)
//
#include <hip/hip_runtime.h>

#define N_NODES 12288
#define IN_F    256
#define OUT_F   64
#define KSPLIT  4
#define MT      64
#define KC      (N_NODES / KSPLIT)   /* 3072 */
#define STEPS   (KC / 32)            /* 96   */

typedef __attribute__((ext_vector_type(8))) short bf16x8;
typedef __attribute__((ext_vector_type(4))) float f32x4;

__device__ __forceinline__ unsigned short f2bf(float f) {
    union { float f; unsigned int i; } v; v.f = f;
    unsigned int x = v.i;
    unsigned int r = x + 0x7FFFu + ((x >> 16) & 1u);  // RNE
    return (unsigned short)(r >> 16);
}

// ---------------- kernel 1: hT[n][i] = bf16( (x @ W)[i][n] )  via MFMA
__global__ __launch_bounds__(256) void k_hT(const float* __restrict__ x,
                                            const float* __restrict__ W,
                                            unsigned short* __restrict__ hT) {
    __shared__ unsigned short WT[OUT_F][IN_F + 8];   // WT[n][k] = bf16(W[k][n])
    int tid = threadIdx.x;
    for (int idx = tid; idx < IN_F * OUT_F; idx += 256) {
        int k = idx >> 6, n = idx & 63;
        WT[n][k] = f2bf(W[idx]);
    }
    __syncthreads();

    int lane = tid & 63, wave = tid >> 6;
    int q = lane >> 4, ml = lane & 15;
    int i0 = blockIdx.x * MT;
    int row = i0 + 16 * wave + ml;
    const float* xr = x + (size_t)row * IN_F + 8 * q;

    f32x4 acc[4];
    #pragma unroll
    for (int nt = 0; nt < 4; ++nt) acc[nt] = (f32x4){0.f, 0.f, 0.f, 0.f};

    #pragma unroll
    for (int kk = 0; kk < IN_F; kk += 32) {
        float4 x0 = *(const float4*)(xr + kk);
        float4 x1 = *(const float4*)(xr + kk + 4);
        union { bf16x8 v; unsigned short u[8]; } A;
        A.u[0] = f2bf(x0.x); A.u[1] = f2bf(x0.y); A.u[2] = f2bf(x0.z); A.u[3] = f2bf(x0.w);
        A.u[4] = f2bf(x1.x); A.u[5] = f2bf(x1.y); A.u[6] = f2bf(x1.z); A.u[7] = f2bf(x1.w);
        #pragma unroll
        for (int nt = 0; nt < 4; ++nt) {
            bf16x8 bv = *(const bf16x8*)&WT[16 * nt + ml][kk + 8 * q];
            acc[nt] = __builtin_amdgcn_mfma_f32_16x16x32_bf16(A.v, bv, acc[nt], 0, 0, 0);
        }
    }

    #pragma unroll
    for (int nt = 0; nt < 4; ++nt) {
        ushort4 o;
        o.x = f2bf(acc[nt][0]); o.y = f2bf(acc[nt][1]);
        o.z = f2bf(acc[nt][2]); o.w = f2bf(acc[nt][3]);
        *(ushort4*)&hT[(size_t)(16 * nt + ml) * N_NODES + i0 + 16 * wave + 4 * q] = o;
    }
}

// ---------------- kernel 2: LDS-free, barrier-free streaming adj @ h
// A-fragment (16x16x32 bf16): lane(ml,q) holds A[ml][8q..8q+7] -> 8 consecutive
// adj int32 loaded as 2x dwordx4, converted in-reg ((lo+(hi<<16))*0x3F80).
// B-fragment: hT[(16nt+ml)*N + k+8q ..+7] -> one dwordx4 from L2-resident hT.
// 2-deep register pipeline (6 KB in flight per wave); no LDS, no __syncthreads.
__global__ __launch_bounds__(256) void k_spmm(const int* __restrict__ adj,
                                              const unsigned short* __restrict__ hT,
                                              float* __restrict__ s_part,
                                              int* __restrict__ deg_part) {
    const int tid  = threadIdx.x;
    const int lane = tid & 63;
    const int wave = tid >> 6;
    const int q    = lane >> 4;
    const int ml   = lane & 15;
    const int i0   = blockIdx.x * MT;
    const int ks   = blockIdx.y;
    const int k0   = ks * KC;
    const int row  = i0 + 16 * wave + ml;

    const int* ap = adj + (size_t)row * N_NODES + k0 + 8 * q;
    const unsigned short* bp = hT + (size_t)ml * N_NODES + k0 + 8 * q;

    f32x4 acc[4];
    #pragma unroll
    for (int nt = 0; nt < 4; ++nt) acc[nt] = (f32x4){0.f, 0.f, 0.f, 0.f};
    unsigned int degp = 0;   // lo 16 bits: even-elem count, hi 16 bits: odd-elem count
                             // (max 4*STEPS = 384 per half, no overflow)

#define LOADS(s, A0, A1, B0, B1, B2, B3) do {                                  \
    A0 = *(const int4*)(ap + 32 * (s));                                        \
    A1 = *(const int4*)(ap + 32 * (s) + 4);                                    \
    B0 = *(const uint4*)(bp + 32 * (s));                                       \
    B1 = *(const uint4*)(bp + (size_t)16 * N_NODES + 32 * (s));                \
    B2 = *(const uint4*)(bp + (size_t)32 * N_NODES + 32 * (s));                \
    B3 = *(const uint4*)(bp + (size_t)48 * N_NODES + 32 * (s));                \
} while (0)

#define COMP(A0, A1, B0, B1, B2, B3) do {                                      \
    unsigned int t0 = (unsigned int)A0.x + ((unsigned int)A0.y << 16);         \
    unsigned int t1 = (unsigned int)A0.z + ((unsigned int)A0.w << 16);         \
    unsigned int t2 = (unsigned int)A1.x + ((unsigned int)A1.y << 16);         \
    unsigned int t3 = (unsigned int)A1.z + ((unsigned int)A1.w << 16);         \
    degp += t0 + t1 + t2 + t3;                                                 \
    union { bf16x8 v; unsigned int w[4]; } av_;                                \
    av_.w[0] = t0 * 0x3F80u; av_.w[1] = t1 * 0x3F80u;                          \
    av_.w[2] = t2 * 0x3F80u; av_.w[3] = t3 * 0x3F80u;                          \
    acc[0] = __builtin_amdgcn_mfma_f32_16x16x32_bf16(av_.v, *(const bf16x8*)&B0, acc[0], 0, 0, 0); \
    acc[1] = __builtin_amdgcn_mfma_f32_16x16x32_bf16(av_.v, *(const bf16x8*)&B1, acc[1], 0, 0, 0); \
    acc[2] = __builtin_amdgcn_mfma_f32_16x16x32_bf16(av_.v, *(const bf16x8*)&B2, acc[2], 0, 0, 0); \
    acc[3] = __builtin_amdgcn_mfma_f32_16x16x32_bf16(av_.v, *(const bf16x8*)&B3, acc[3], 0, 0, 0); \
} while (0)

    int4 a0A, a1A; uint4 b0A, b1A, b2A, b3A;
    int4 a0B, a1B; uint4 b0B, b1B, b2B, b3B;

    LOADS(0, a0A, a1A, b0A, b1A, b2A, b3A);
    for (int s = 0; s < STEPS - 2; s += 2) {
        LOADS(s + 1, a0B, a1B, b0B, b1B, b2B, b3B);
        COMP(a0A, a1A, b0A, b1A, b2A, b3A);
        LOADS(s + 2, a0A, a1A, b0A, b1A, b2A, b3A);
        COMP(a0B, a1B, b0B, b1B, b2B, b3B);
    }
    LOADS(STEPS - 1, a0B, a1B, b0B, b1B, b2B, b3B);
    COMP(a0A, a1A, b0A, b1A, b2A, b3A);
    COMP(a0B, a1B, b0B, b1B, b2B, b3B);

#undef LOADS
#undef COMP

    // epilogue: non-atomic partial store (each block owns its 64x64 region of slice ks)
    float* sp = s_part + (size_t)ks * ((size_t)N_NODES * OUT_F);
    #pragma unroll
    for (int nt = 0; nt < 4; ++nt) {
        #pragma unroll
        for (int rr = 0; rr < 4; ++rr) {
            int orow = i0 + 16 * wave + 4 * q + rr;   // C layout: row = quad*4+reg
            int ocol = 16 * nt + ml;                  // col = lane&15
            sp[(size_t)orow * OUT_F + ocol] = acc[nt][rr];
        }
    }

    // degree: reduce the packed counter across the 4 q-lanes of this row, fold halves
    degp += (unsigned int)__shfl_xor((int)degp, 16, 64);
    degp += (unsigned int)__shfl_xor((int)degp, 32, 64);
    int deg = (int)((degp & 0xFFFFu) + (degp >> 16));
    if (q == 0)
        deg_part[ks * N_NODES + row] = deg;
}

// ---------------- kernel 3: out = elu( sum_p s_part / sum_p deg_part ), fp32
__global__ __launch_bounds__(256) void k_out(const float* __restrict__ s_part,
                                             const int* __restrict__ deg_part,
                                             float* __restrict__ out) {
    int idx = blockIdx.x * 256 + threadIdx.x;
    int i = idx >> 6;
    float s = 0.f; int deg = 0;
    #pragma unroll
    for (int p = 0; p < KSPLIT; ++p) {
        s   += s_part[(size_t)p * ((size_t)N_NODES * OUT_F) + idx];
        deg += deg_part[p * N_NODES + i];
    }
    float v = (deg > 0) ? (s / (float)deg) : 0.f;
    out[idx] = (v > 0.f) ? v : expm1f(v);
}

extern "C" void kernel_launch(void* const* d_in, const int* in_sizes, int n_in,
                              void* d_out, int out_size, void* d_ws, size_t ws_size,
                              hipStream_t stream) {
    const int*   adj = (const int*)d_in[0];
    const float* x   = (const float*)d_in[1];   // fp32
    const float* W   = (const float*)d_in[2];   // fp32
    // d_in[3] (a) provably cancels out of the output — unused.
    float* out = (float*)d_out;                 // fp32

    char* ws = (char*)d_ws;
    const size_t hT_bytes = (size_t)N_NODES * OUT_F * 2;                 // 1.5 MB
    const size_t sp_bytes = (size_t)KSPLIT * N_NODES * OUT_F * 4;        // 12.6 MB
    unsigned short* hT = (unsigned short*)ws;
    float* s_part      = (float*)(ws + hT_bytes);
    int*   deg_part    = (int*)(ws + hT_bytes + sp_bytes);
    // total ~14.3 MB of d_ws (matches the harness-proven footprint)

    k_hT  <<<dim3(N_NODES / MT),          dim3(256), 0, stream>>>(x, W, hT);
    k_spmm<<<dim3(N_NODES / MT, KSPLIT),  dim3(256), 0, stream>>>(adj, hT, s_part, deg_part);
    k_out <<<dim3(N_NODES * OUT_F / 256), dim3(256), 0, stream>>>(s_part, deg_part, out);
}

// Round 3
// 851.942 us; speedup vs baseline: 1.0519x; 1.0519x over previous
//
#include <hip/hip_runtime.h>

#define N_NODES 12288
#define IN_F    256
#define OUT_F   64
#define KSPLIT  4
#define MT      64
#define KC      (N_NODES / KSPLIT)   /* 3072 */
#define BK      128
#define STEPS   (KC / BK)            /* 24 */
#define AST     144                  /* LDS row stride in shorts: BK + 16 pad */

typedef __attribute__((ext_vector_type(8))) short bf16x8;
typedef __attribute__((ext_vector_type(4))) float f32x4;

__device__ __forceinline__ unsigned short f2bf(float f) {
    union { float f; unsigned int i; } v; v.f = f;
    unsigned int x = v.i;
    unsigned int r = x + 0x7FFFu + ((x >> 16) & 1u);  // RNE
    return (unsigned short)(r >> 16);
}

// ---------------- kernel 1: hT[n][i] = bf16( (x @ W)[i][n] )  via MFMA
__global__ __launch_bounds__(256) void k_hT(const float* __restrict__ x,
                                            const float* __restrict__ W,
                                            unsigned short* __restrict__ hT) {
    __shared__ unsigned short WT[OUT_F][IN_F + 8];   // WT[n][k] = bf16(W[k][n])
    int tid = threadIdx.x;
    for (int idx = tid; idx < IN_F * OUT_F; idx += 256) {
        int k = idx >> 6, n = idx & 63;
        WT[n][k] = f2bf(W[idx]);
    }
    __syncthreads();

    int lane = tid & 63, wave = tid >> 6;
    int q = lane >> 4, ml = lane & 15;
    int i0 = blockIdx.x * MT;
    int row = i0 + 16 * wave + ml;
    const float* xr = x + (size_t)row * IN_F + 8 * q;

    f32x4 acc[4];
    #pragma unroll
    for (int nt = 0; nt < 4; ++nt) acc[nt] = (f32x4){0.f, 0.f, 0.f, 0.f};

    #pragma unroll
    for (int kk = 0; kk < IN_F; kk += 32) {
        float4 x0 = *(const float4*)(xr + kk);
        float4 x1 = *(const float4*)(xr + kk + 4);
        union { bf16x8 v; unsigned short u[8]; } A;
        A.u[0] = f2bf(x0.x); A.u[1] = f2bf(x0.y); A.u[2] = f2bf(x0.z); A.u[3] = f2bf(x0.w);
        A.u[4] = f2bf(x1.x); A.u[5] = f2bf(x1.y); A.u[6] = f2bf(x1.z); A.u[7] = f2bf(x1.w);
        #pragma unroll
        for (int nt = 0; nt < 4; ++nt) {
            bf16x8 bv = *(const bf16x8*)&WT[16 * nt + ml][kk + 8 * q];
            acc[nt] = __builtin_amdgcn_mfma_f32_16x16x32_bf16(A.v, bv, acc[nt], 0, 0, 0);
        }
    }

    #pragma unroll
    for (int nt = 0; nt < 4; ++nt) {
        ushort4 o;
        o.x = f2bf(acc[nt][0]); o.y = f2bf(acc[nt][1]);
        o.z = f2bf(acc[nt][2]); o.w = f2bf(acc[nt][3]);
        *(ushort4*)&hT[(size_t)(16 * nt + ml) * N_NODES + i0 + 16 * wave + 4 * q] = o;
    }
}

// ---------------- kernel 2: burst-staged, barrier-free adj @ h
// Each wave owns 16 adj rows. Per step it stages 16 rows x 128 ints with ONE
// dwordx2 wave-load per row (512B contiguous burst -> dense 64B transactions,
// one DRAM page visit per 512B instead of per 128B), converts 0/1 -> bf16 in
// regs, ds_writes into a wave-private double-buffered LDS tile. No barriers.
// Degree comes free via a 5th MFMA against an all-ones B fragment (exact).
__global__ __launch_bounds__(256) void k_spmm(const int* __restrict__ adj,
                                              const unsigned short* __restrict__ hT,
                                              float* __restrict__ s_part,
                                              float* __restrict__ deg_part) {
    __shared__ __align__(16) unsigned short As[2][4][16][AST];   // 36.9 KB

    const int tid  = threadIdx.x;
    const int lane = tid & 63;
    const int wave = tid >> 6;
    const int q    = lane >> 4;
    const int ml   = lane & 15;
    const int i0   = blockIdx.x * MT;
    const int ks   = blockIdx.y;
    const int k0   = ks * KC;

    // staging: lane l covers ints [2l, 2l+2) of each of this wave's 16 rows
    const int* arow = adj + (size_t)(i0 + 16 * wave) * N_NODES + k0 + 2 * lane;
    // B fragments: proven direct-from-global pattern (L1/L2-resident hT)
    const unsigned short* bp = hT + (size_t)ml * N_NODES + k0 + 8 * q;

    union { bf16x8 v; unsigned short u[8]; } ones;
    #pragma unroll
    for (int i = 0; i < 8; ++i) ones.u[i] = 0x3F80;

    f32x4 acc[4], accd;
    #pragma unroll
    for (int nt = 0; nt < 4; ++nt) acc[nt] = (f32x4){0.f, 0.f, 0.f, 0.f};
    accd = (f32x4){0.f, 0.f, 0.f, 0.f};

    int2 st[16];

#define STAGE_ISSUE(sidx) do {                                                 \
    const int* ap_ = arow + (size_t)(sidx) * BK;                               \
    _Pragma("unroll")                                                          \
    for (int rr = 0; rr < 16; ++rr)                                            \
        st[rr] = *(const int2*)(ap_ + (size_t)rr * N_NODES);                   \
} while (0)

#define STAGE_WRITE(b) do {                                                    \
    _Pragma("unroll")                                                          \
    for (int rr = 0; rr < 16; ++rr) {                                          \
        unsigned int t = ((unsigned int)st[rr].x +                             \
                          ((unsigned int)st[rr].y << 16)) * 0x3F80u;           \
        *(unsigned int*)&As[b][wave][rr][2 * lane] = t;                        \
    }                                                                          \
} while (0)

#define BLOAD(koff, B0, B1, B2, B3) do {                                       \
    const unsigned short* bq = bp + (koff);                                    \
    B0 = *(const uint4*)(bq);                                                  \
    B1 = *(const uint4*)(bq + (size_t)16 * N_NODES);                           \
    B2 = *(const uint4*)(bq + (size_t)32 * N_NODES);                           \
    B3 = *(const uint4*)(bq + (size_t)48 * N_NODES);                           \
} while (0)

#define COMP(j, b, B0, B1, B2, B3) do {                                        \
    bf16x8 av = *(const bf16x8*)&As[b][wave][ml][32 * (j) + 8 * q];            \
    acc[0] = __builtin_amdgcn_mfma_f32_16x16x32_bf16(av, *(const bf16x8*)&B0, acc[0], 0, 0, 0); \
    acc[1] = __builtin_amdgcn_mfma_f32_16x16x32_bf16(av, *(const bf16x8*)&B1, acc[1], 0, 0, 0); \
    acc[2] = __builtin_amdgcn_mfma_f32_16x16x32_bf16(av, *(const bf16x8*)&B2, acc[2], 0, 0, 0); \
    acc[3] = __builtin_amdgcn_mfma_f32_16x16x32_bf16(av, *(const bf16x8*)&B3, acc[3], 0, 0, 0); \
    accd   = __builtin_amdgcn_mfma_f32_16x16x32_bf16(av, ones.v,               accd,   0, 0, 0); \
} while (0)

    uint4 b0A, b1A, b2A, b3A;
    uint4 b0B, b1B, b2B, b3B;

    // prologue: stage step 0 into buf 0, preload B for subk 0
    STAGE_ISSUE(0);
    STAGE_WRITE(0);
    BLOAD(0, b0A, b1A, b2A, b3A);

    for (int s = 0; s < STEPS; ++s) {
        const int b  = s & 1;
        const int s1 = (s + 1 < STEPS) ? s + 1 : 0;   // clamp: keeps last-iter prefetch in-bounds (data unused)

        STAGE_ISSUE(s1);                               // 16 x 512B row bursts, hidden under this step's compute

        BLOAD(BK * s + 32, b0B, b1B, b2B, b3B);
        COMP(0, b, b0A, b1A, b2A, b3A);
        BLOAD(BK * s + 64, b0A, b1A, b2A, b3A);
        COMP(1, b, b0B, b1B, b2B, b3B);
        BLOAD(BK * s + 96, b0B, b1B, b2B, b3B);
        COMP(2, b, b0A, b1A, b2A, b3A);
        BLOAD(BK * s1,     b0A, b1A, b2A, b3A);        // next step's subk 0
        COMP(3, b, b0B, b1B, b2B, b3B);

        STAGE_WRITE(b ^ 1);                            // wave-private buffer: no barrier needed
    }

#undef STAGE_ISSUE
#undef STAGE_WRITE
#undef BLOAD
#undef COMP

    // epilogue: non-atomic partial store (each block owns its 64x64 region of slice ks)
    float* sp = s_part + (size_t)ks * ((size_t)N_NODES * OUT_F);
    #pragma unroll
    for (int nt = 0; nt < 4; ++nt) {
        #pragma unroll
        for (int rr = 0; rr < 4; ++rr) {
            int orow = i0 + 16 * wave + 4 * q + rr;   // C layout: row = quad*4+reg
            int ocol = 16 * nt + ml;                  // col = lane&15
            sp[(size_t)orow * OUT_F + ocol] = acc[nt][rr];
        }
    }

    // degree: C[m][n] of ones-MFMA is row-degree in every column; take col 0 (ml==0 lanes)
    if (ml == 0) {
        #pragma unroll
        for (int rr = 0; rr < 4; ++rr)
            deg_part[ks * N_NODES + i0 + 16 * wave + 4 * q + rr] = accd[rr];
    }
}

// ---------------- kernel 3: out = elu( sum_p s_part / sum_p deg_part ), fp32
__global__ __launch_bounds__(256) void k_out(const float* __restrict__ s_part,
                                             const float* __restrict__ deg_part,
                                             float* __restrict__ out) {
    int idx = blockIdx.x * 256 + threadIdx.x;
    int i = idx >> 6;
    float s = 0.f, deg = 0.f;
    #pragma unroll
    for (int p = 0; p < KSPLIT; ++p) {
        s   += s_part[(size_t)p * ((size_t)N_NODES * OUT_F) + idx];
        deg += deg_part[p * N_NODES + i];
    }
    float v = (deg > 0.5f) ? (s / deg) : 0.f;
    out[idx] = (v > 0.f) ? v : expm1f(v);
}

extern "C" void kernel_launch(void* const* d_in, const int* in_sizes, int n_in,
                              void* d_out, int out_size, void* d_ws, size_t ws_size,
                              hipStream_t stream) {
    const int*   adj = (const int*)d_in[0];
    const float* x   = (const float*)d_in[1];   // fp32
    const float* W   = (const float*)d_in[2];   // fp32
    // d_in[3] (a) provably cancels out of the output — unused.
    float* out = (float*)d_out;                 // fp32

    char* ws = (char*)d_ws;
    const size_t hT_bytes = (size_t)N_NODES * OUT_F * 2;                 // 1.5 MB
    const size_t sp_bytes = (size_t)KSPLIT * N_NODES * OUT_F * 4;        // 12.6 MB
    unsigned short* hT = (unsigned short*)ws;
    float* s_part      = (float*)(ws + hT_bytes);
    float* deg_part    = (float*)(ws + hT_bytes + sp_bytes);
    // total ~14.3 MB of d_ws (matches the harness-proven footprint)

    k_hT  <<<dim3(N_NODES / MT),          dim3(256), 0, stream>>>(x, W, hT);
    k_spmm<<<dim3(N_NODES / MT, KSPLIT),  dim3(256), 0, stream>>>(adj, hT, s_part, deg_part);
    k_out <<<dim3(N_NODES * OUT_F / 256), dim3(256), 0, stream>>>(s_part, deg_part, out);
}